// Round 1
// baseline (1205.686 us; speedup 1.0000x reference)
//
#include <hip/hip_runtime.h>
#include <cmath>

#define Bsz 64
#define Tt  512
#define Dd  768
#define Wn  255
#define Hh  8
#define DHd 96
#define NROWS (Bsz*Wn)   // 16320

typedef _Float16 half_t;
typedef _Float16 f16x8 __attribute__((ext_vector_type(8)));
typedef _Float16 f16x4 __attribute__((ext_vector_type(4)));
typedef float f32x4 __attribute__((ext_vector_type(4)));

// ---- split-fp16 weights as concatenated-K B' panels: [N][3K] = [Bh | Bh | Bl]
// A' = [Ah | Al | Ah] handled by per-tile source mapping. scales: W x64, act x16,
// epilogue descale 1/1024. ~40.5 MiB static device memory.
#define OFF_QKV 0            // 2304 x 2304
#define OFF_WO  5308416      //  768 x 2304
#define OFF_W1  7077888      // 3072 x 2304
#define OFF_W2  14155776     // 3 chunks x [768 x 3072]  (K split 1024 each)
#define SLOTH 25165824       // halves per 48 MiB workspace slot (q16->k16->v16)
__device__ __align__(16) half_t g_w16[21233664];

__device__ __forceinline__ void gload16(const half_t* g, half_t* l) {
    __builtin_amdgcn_global_load_lds((const __attribute__((address_space(1))) void*)g,
                                     (__attribute__((address_space(3))) void*)l, 16, 0, 0);
}

// ---------------- gather: first-subtoken index + feature copy ----------------

__global__ void k_init_fi(int* fi) {
    int i = blockIdx.x * 256 + threadIdx.x;
    if (i < Bsz * Wn) fi[i] = 0x7fffffff;
}

__global__ void k_scan(const int* __restrict__ wid, int* __restrict__ fi) {
    int i = blockIdx.x * 256 + threadIdx.x;   // over B*T
    if (i >= Bsz * Tt) return;
    int b = i / Tt, t = i % Tt;
    int w = wid[i];
    if (w >= 0 && w < Wn) atomicMin(&fi[b * Wn + w], t);
}

__global__ void k_bcat(const float* __restrict__ bq, const float* __restrict__ bk,
                       const float* __restrict__ bv, float* __restrict__ o) {
    int i = blockIdx.x * 256 + threadIdx.x;
    if (i < 768) o[i] = bq[i];
    else if (i < 1536) o[i] = bk[i - 768];
    else if (i < 2304) o[i] = bv[i - 1536];
}

// gather directly into interleaved fp16 hi/lo records (row = 1536 halves: hi[768]|lo[768])
__global__ void k_gather(const float4* __restrict__ ob, const int* __restrict__ fi,
                         half_t* __restrict__ f16) {
    int i = blockIdx.x * 256 + threadIdx.x;   // over NROWS*192
    if (i >= NROWS * 192) return;
    int r = i / 192, c = i % 192;
    int b = r / Wn;
    int idx = fi[r];
    if (idx == 0x7fffffff) idx = 0;           // argmax(all-False) == 0
    float4 v = ob[((size_t)b * Tt + idx) * 192 + c];
    float a0 = v.x * 16.f, a1 = v.y * 16.f, a2 = v.z * 16.f, a3 = v.w * 16.f;
    half_t h0 = (half_t)a0, h1 = (half_t)a1, h2 = (half_t)a2, h3 = (half_t)a3;
    f16x4 hv = {h0, h1, h2, h3};
    f16x4 lv = {(half_t)(a0 - (float)h0), (half_t)(a1 - (float)h1),
                (half_t)(a2 - (float)h2), (half_t)(a3 - (float)h3)};
    size_t off = (size_t)r * 1536 + c * 4;
    *(f16x4*)&f16[off] = hv;
    *(f16x4*)&f16[off + 768] = lv;
}

// ---- weight transpose+split: W[K,N] -> B'[n][3*Kseg] = [hi|hi|lo], chunked by Kseg

__global__ void k_wsplit(const float* __restrict__ Wm, int K, int N,
                         size_t obase, int Kseg, size_t cstride) {
    __shared__ float sm[32][33];
    const int tx = threadIdx.x, ty = threadIdx.y;
    const int n0 = blockIdx.x * 32, k0 = blockIdx.y * 32;
    #pragma unroll
    for (int r = 0; r < 4; ++r)
        sm[ty + r * 8][tx] = Wm[(size_t)(k0 + ty + r * 8) * N + n0 + tx];
    __syncthreads();
    #pragma unroll
    for (int r = 0; r < 4; ++r) {
        float v = 64.f * sm[tx][ty + r * 8];
        half_t hi = (half_t)v;
        half_t lo = (half_t)(v - (float)hi);
        int k = k0 + tx;
        int n = n0 + ty + r * 8;
        int c = k / Kseg, kk = k - c * Kseg;
        half_t* o = g_w16 + obase + (size_t)c * cstride + (size_t)n * (3 * Kseg) + kk;
        o[0] = hi; o[Kseg] = hi; o[2 * Kseg] = lo;
    }
}

// ---------------- 256x256 split-fp16 MFMA GEMM, counted-vmcnt schedule -------
// 512 thr = 8 waves (2M x 4N), per-wave 128x64 out, BK=64, dbuf LDS 128 KiB.
// LDS layout per buffer: A [4 chunks of 64x64] then B [4 chunks of 64x64];
// each chunk row-major, col-chunk XOR-swizzled (j ^= row&7) via pre-swizzled
// global source (gload_lds writes linearly) + swizzled ds_read -> 2-way (free).
// Per K-tile (=64) two sub-phases of 32 MFMA. Stage issue order per tile:
// sub0 issues next-tile B0..B3, sub1 issues A0,A2,A1,A3. Waits: vmcnt(4)
// mid-tile (drains A1,A3; leaves B0..3), vmcnt(2) at tile boundary (leaves
// A1,A3). Never drains to 0 in steady state. Raw s_barrier + setprio on MFMA.
// K' = 3K concat: tile segment 0 -> Ah, 1 -> Al, 2 -> Ah (B' rows prebuilt).
// MODE 5: fused QKV -> q16/k16/v16 head-major [bh][256][hi96|lo96]
// MODE 1: fp32 out + interleaved fp16-pair residual (O-proj); AMODE 1: A = ctx head-major
// MODE 2: relu -> fp16 hi/lo plane pair x16 (FFN1 N-chunk)
// MODE 3: fp32 out = acc + bias + res (in-place over res OK: same-thread RMW)
// MODE 4: fp32 out += acc (no bias) -- FFN2 K-chunk accumulation

__device__ __forceinline__ void stage_b(const half_t* B, int Kp3, int col0,
                                        int t, int c, half_t* dst, int tid) {
    int gc = col0 + c * 64 + (tid >> 3);
    int sj = (tid & 7) ^ ((tid >> 3) & 7);
    gload16(B + (size_t)gc * Kp3 + (size_t)t * 64 + sj * 8,
            dst + 16384 + c * 4096 + (tid >> 6) * 512);
}

__device__ __forceinline__ void stage_a0(const half_t* Ap, int lda, int row0, int M,
                                         int kk, int c, half_t* dst, int tid) {
    int gr = row0 + c * 64 + (tid >> 3); if (gr > M - 1) gr = M - 1;
    int sj = (tid & 7) ^ ((tid >> 3) & 7);
    gload16(Ap + (size_t)gr * lda + kk + sj * 8, dst + c * 4096 + (tid >> 6) * 512);
}

__device__ __forceinline__ void stage_a1(const half_t* qcb, int row0, int M,
                                         int kk, int soff, int c, half_t* dst, int tid) {
    int gr = row0 + c * 64 + (tid >> 3); if (gr > M - 1) gr = M - 1;
    int sj = (tid & 7) ^ ((tid >> 3) & 7);
    int k = kk + sj * 8;
    int h = k / 96, d = k - h * 96;
    int b = gr / 255, wl = gr - b * 255;
    gload16(qcb + ((size_t)(b * 8 + h) * 256 + wl) * 192 + d + soff,
            dst + c * 4096 + (tid >> 6) * 512);
}

template<int MODE, int AMODE>
__global__ __launch_bounds__(512, 2) void k_gemm256(
    const half_t* __restrict__ Ah, const half_t* __restrict__ Al, int lda,
    size_t boff, const float* __restrict__ bias,
    const void* res, void* out0, void* out1,
    int M, int N, int K) {
    __shared__ half_t sm[2][32768];
    const int tid = threadIdx.x;
    const int w = tid >> 6, l = tid & 63;
    const int wm = w >> 2, wn = w & 3;
    const int fr = l & 15, q4 = l >> 4;
    const int ck0 = (q4 * 8) ^ ((fr & 7) << 3);   // swizzled col (halves), ks=0
    const int ck1 = ck0 ^ 32;                     // ks=1
    const half_t* Bsrc = g_w16 + boff;
    const int Kp3 = 3 * K, NT = Kp3 >> 6;

    // XCD-locality swizzle (nwg % 8 == 0 for all our grids)
    int lin = blockIdx.y * gridDim.x + blockIdx.x;
    int nwg = gridDim.x * gridDim.y;
    int wg = (lin & 7) * (nwg >> 3) + (lin >> 3);
    int by = wg / gridDim.x, bx = wg - by * gridDim.x;
    const int row0 = by * 256, col0 = bx * 256;

    f32x4 acc[8][4];
    #pragma unroll
    for (int m = 0; m < 8; ++m)
        #pragma unroll
        for (int n = 0; n < 4; ++n) acc[m][n] = (f32x4){0.f, 0.f, 0.f, 0.f};

    // prologue: stage tile 0 in steady-state issue order [B0..B3, A0,A2,A1,A3]
    {
        half_t* d0 = &sm[0][0];
        stage_b(Bsrc, Kp3, col0, 0, 0, d0, tid);
        stage_b(Bsrc, Kp3, col0, 0, 1, d0, tid);
        stage_b(Bsrc, Kp3, col0, 0, 2, d0, tid);
        stage_b(Bsrc, Kp3, col0, 0, 3, d0, tid);
        if (AMODE == 0) {
            stage_a0(Ah, lda, row0, M, 0, 0, d0, tid);
            stage_a0(Ah, lda, row0, M, 0, 2, d0, tid);
            stage_a0(Ah, lda, row0, M, 0, 1, d0, tid);
            stage_a0(Ah, lda, row0, M, 0, 3, d0, tid);
        } else {
            stage_a1(Ah, row0, M, 0, 0, 0, d0, tid);
            stage_a1(Ah, row0, M, 0, 0, 2, d0, tid);
            stage_a1(Ah, row0, M, 0, 0, 1, d0, tid);
            stage_a1(Ah, row0, M, 0, 0, 3, d0, tid);
        }
    }
    asm volatile("s_waitcnt vmcnt(2)" ::: "memory");
    __builtin_amdgcn_s_barrier();
    asm volatile("" ::: "memory");

    for (int t = 0; t < NT; ++t) {
        const int p = t & 1;
        half_t* nxtb = &sm[p ^ 1][0];
        const half_t* pA = &sm[p][0] + wm * 8192;
        const half_t* pB = &sm[p][0] + 16384 + wn * 4096;
        const bool pf = (t + 1) < NT;
        const int kn = (t + 1) << 6;
        const int seg = (kn >= 2 * K) ? 2 : ((kn >= K) ? 1 : 0);
        const int kkn = kn - seg * K;
        const half_t* An = (seg == 1) ? Al : Ah;
        const int soff = (seg == 1) ? 96 : 0;

        // ---- sub0: B frags (held for whole tile) + A m0..3, stage next B ----
        f16x8 b0[4], b1[4], a0[4], a1[4];
        #pragma unroll
        for (int n = 0; n < 4; ++n) {
            b0[n] = *(const f16x8*)&pB[n * 1024 + fr * 64 + ck0];
            b1[n] = *(const f16x8*)&pB[n * 1024 + fr * 64 + ck1];
        }
        #pragma unroll
        for (int m = 0; m < 4; ++m) {
            a0[m] = *(const f16x8*)&pA[m * 1024 + fr * 64 + ck0];
            a1[m] = *(const f16x8*)&pA[m * 1024 + fr * 64 + ck1];
        }
        if (pf) {
            stage_b(Bsrc, Kp3, col0, t + 1, 0, nxtb, tid);
            stage_b(Bsrc, Kp3, col0, t + 1, 1, nxtb, tid);
            stage_b(Bsrc, Kp3, col0, t + 1, 2, nxtb, tid);
            stage_b(Bsrc, Kp3, col0, t + 1, 3, nxtb, tid);
        }
        __builtin_amdgcn_s_setprio(1);
        #pragma unroll
        for (int m = 0; m < 4; ++m)
            #pragma unroll
            for (int n = 0; n < 4; ++n) {
                acc[m][n] = __builtin_amdgcn_mfma_f32_16x16x32_f16(a0[m], b0[n], acc[m][n], 0, 0, 0);
                acc[m][n] = __builtin_amdgcn_mfma_f32_16x16x32_f16(a1[m], b1[n], acc[m][n], 0, 0, 0);
            }
        __builtin_amdgcn_s_setprio(0);
        if (pf) asm volatile("s_waitcnt vmcnt(4)" ::: "memory");
        else    asm volatile("s_waitcnt vmcnt(0)" ::: "memory");
        __builtin_amdgcn_s_barrier();
        asm volatile("" ::: "memory");

        // ---- sub1: A m4..7, stage next A (order 0,2,1,3) ----
        #pragma unroll
        for (int m = 0; m < 4; ++m) {
            a0[m] = *(const f16x8*)&pA[4096 + m * 1024 + fr * 64 + ck0];
            a1[m] = *(const f16x8*)&pA[4096 + m * 1024 + fr * 64 + ck1];
        }
        if (pf) {
            if (AMODE == 0) {
                stage_a0(An, lda, row0, M, kkn, 0, nxtb, tid);
                stage_a0(An, lda, row0, M, kkn, 2, nxtb, tid);
                stage_a0(An, lda, row0, M, kkn, 1, nxtb, tid);
                stage_a0(An, lda, row0, M, kkn, 3, nxtb, tid);
            } else {
                stage_a1(Ah, row0, M, kkn, soff, 0, nxtb, tid);
                stage_a1(Ah, row0, M, kkn, soff, 2, nxtb, tid);
                stage_a1(Ah, row0, M, kkn, soff, 1, nxtb, tid);
                stage_a1(Ah, row0, M, kkn, soff, 3, nxtb, tid);
            }
        }
        __builtin_amdgcn_s_setprio(1);
        #pragma unroll
        for (int m = 0; m < 4; ++m)
            #pragma unroll
            for (int n = 0; n < 4; ++n) {
                acc[4 + m][n] = __builtin_amdgcn_mfma_f32_16x16x32_f16(a0[m], b0[n], acc[4 + m][n], 0, 0, 0);
                acc[4 + m][n] = __builtin_amdgcn_mfma_f32_16x16x32_f16(a1[m], b1[n], acc[4 + m][n], 0, 0, 0);
            }
        __builtin_amdgcn_s_setprio(0);
        if (pf) {
            asm volatile("s_waitcnt vmcnt(2)" ::: "memory");
            __builtin_amdgcn_s_barrier();
            asm volatile("" ::: "memory");
        }
    }

    // ---- epilogue ----
    const float dsc = 1.0f / 1024.0f;
    #pragma unroll
    for (int m = 0; m < 8; ++m) {
        #pragma unroll
        for (int r = 0; r < 4; ++r) {
            const int row = row0 + wm * 128 + m * 16 + q4 * 4 + r;
            if (row >= M) continue;
            #pragma unroll
            for (int n = 0; n < 4; ++n) {
                const int col = col0 + wn * 64 + n * 16 + fr;
                float vv = acc[m][n][r] * dsc;
                if (MODE != 4) vv += bias[col];
                if (MODE == 5) {
                    int part = col / 768, cc = col - part * 768;
                    int h = cc / 96, d = cc - h * 96;
                    int b = row / 255, wl = row - b * 255;
                    float t16 = vv * 16.f;
                    half_t hi = (half_t)t16;
                    half_t lo = (half_t)(t16 - (float)hi);
                    half_t* dstp = (half_t*)out0 + (size_t)part * SLOTH;
                    size_t o = ((size_t)(b * 8 + h) * 256 + wl) * 192 + d;
                    dstp[o] = hi; dstp[o + 96] = lo;
                } else if (MODE == 1) {
                    const half_t* rp = (const half_t*)res;
                    vv += ((float)rp[(size_t)row * 1536 + col] +
                           (float)rp[(size_t)row * 1536 + 768 + col]) * 0.0625f;
                    ((float*)out0)[(size_t)row * N + col] = vv;
                } else if (MODE == 2) {
                    vv = fmaxf(vv, 0.f);
                    float t16 = vv * 16.f;
                    half_t hi = (half_t)t16;
                    ((half_t*)out0)[(size_t)row * N + col] = hi;
                    ((half_t*)out1)[(size_t)row * N + col] = (half_t)(t16 - (float)hi);
                } else if (MODE == 3) {
                    vv += ((const float*)res)[(size_t)row * N + col];
                    ((float*)out0)[(size_t)row * N + col] = vv;
                } else {   // MODE 4: accumulate (same-thread RMW, stream-serialized)
                    float* op = (float*)out0 + (size_t)row * N + col;
                    *op += vv;
                }
            }
        }
    }
}

// ---------------- flash MFMA attention, split-fp16, one block per (b,h) ------
// (unchanged from previous verified version)

__global__ __launch_bounds__(256, 2) void k_attn2(half_t* __restrict__ qc,
                                                  const half_t* __restrict__ kk16,
                                                  const half_t* __restrict__ vv16) {
    __shared__ half_t sK[64][200];
    __shared__ half_t sVT[192][72];
    __shared__ float  sP[4][16][68];
    const int tid = threadIdx.x;
    const int w = tid >> 6, l = tid & 63;
    const int lr = l & 15, lc = l >> 4;
    const size_t base = (size_t)blockIdx.x * 49152;
    const float ssc = 0.10206207261596575f / 256.0f;

    for (int pass = 0; pass < 2; ++pass) {
        f32x4 O[2][6];
        float mrow[2][4], lrow[2][4];
        #pragma unroll
        for (int qs = 0; qs < 2; ++qs) {
            #pragma unroll
            for (int dn = 0; dn < 6; ++dn) O[qs][dn] = (f32x4){0.f, 0.f, 0.f, 0.f};
            #pragma unroll
            for (int r = 0; r < 4; ++r) { mrow[qs][r] = -3e38f; lrow[qs][r] = 0.f; }
        }
        for (int kt = 0; kt < 4; ++kt) {
            __syncthreads();
            #pragma unroll
            for (int c = 0; c < 6; ++c) {
                int ch = w + c * 4;
                *(f16x8*)&sK[l][ch * 8] =
                    *(const f16x8*)(kk16 + base + (size_t)(kt * 64 + l) * 192 + ch * 8);
            }
            #pragma unroll
            for (int c = 0; c < 6; ++c) {
                int ch = w + c * 4;
                f16x8 vv = *(const f16x8*)(vv16 + base + (size_t)(kt * 64 + l) * 192 + ch * 8);
                #pragma unroll
                for (int j = 0; j < 8; ++j) sVT[ch * 8 + j][l] = vv[j];
            }
            __syncthreads();
            #pragma unroll
            for (int qs = 0; qs < 2; ++qs) {
                const int qrow0 = (pass * 2 + qs) * 64 + w * 16;
                f16x8 qf0[3], qf1[3];
                #pragma unroll
                for (int s = 0; s < 3; ++s) {
                    qf0[s] = *(const f16x8*)(qc + base + (size_t)(qrow0 + lr) * 192 + s * 32 + lc * 8);
                    qf1[s] = *(const f16x8*)(qc + base + (size_t)(qrow0 + lr) * 192 + 96 + s * 32 + lc * 8);
                }
                f32x4 sacc[4];
                #pragma unroll
                for (int nt = 0; nt < 4; ++nt) sacc[nt] = (f32x4){0.f, 0.f, 0.f, 0.f};
                #pragma unroll
                for (int s = 0; s < 3; ++s)
                    #pragma unroll
                    for (int nt = 0; nt < 4; ++nt) {
                        f16x8 kh = *(const f16x8*)&sK[nt * 16 + lr][s * 32 + lc * 8];
                        f16x8 klo = *(const f16x8*)&sK[nt * 16 + lr][96 + s * 32 + lc * 8];
                        sacc[nt] = __builtin_amdgcn_mfma_f32_16x16x32_f16(qf0[s], kh, sacc[nt], 0, 0, 0);
                        sacc[nt] = __builtin_amdgcn_mfma_f32_16x16x32_f16(qf0[s], klo, sacc[nt], 0, 0, 0);
                        sacc[nt] = __builtin_amdgcn_mfma_f32_16x16x32_f16(qf1[s], kh, sacc[nt], 0, 0, 0);
                    }
                float sv[4][4], mx[4] = {-3e38f, -3e38f, -3e38f, -3e38f};
                #pragma unroll
                for (int nt = 0; nt < 4; ++nt) {
                    int key = kt * 64 + nt * 16 + lr;
                    #pragma unroll
                    for (int r = 0; r < 4; ++r) {
                        float s_ = sacc[nt][r] * ssc;
                        if (key >= 255) s_ = -3e38f;
                        sv[nt][r] = s_;
                        mx[r] = fmaxf(mx[r], s_);
                    }
                }
                #pragma unroll
                for (int r = 0; r < 4; ++r) {
                    mx[r] = fmaxf(mx[r], __shfl_xor(mx[r], 1));
                    mx[r] = fmaxf(mx[r], __shfl_xor(mx[r], 2));
                    mx[r] = fmaxf(mx[r], __shfl_xor(mx[r], 4));
                    mx[r] = fmaxf(mx[r], __shfl_xor(mx[r], 8));
                }
                float alpha[4], rsum[4];
                #pragma unroll
                for (int r = 0; r < 4; ++r) {
                    float mn = fmaxf(mrow[qs][r], mx[r]);
                    alpha[r] = __expf(mrow[qs][r] - mn);
                    mrow[qs][r] = mn;
                    rsum[r] = 0.f;
                }
                float pv[4][4];
                #pragma unroll
                for (int nt = 0; nt < 4; ++nt)
                    #pragma unroll
                    for (int r = 0; r < 4; ++r) {
                        float p = __expf(sv[nt][r] - mrow[qs][r]);
                        pv[nt][r] = p;
                        rsum[r] += p;
                    }
                #pragma unroll
                for (int r = 0; r < 4; ++r) {
                    rsum[r] += __shfl_xor(rsum[r], 1);
                    rsum[r] += __shfl_xor(rsum[r], 2);
                    rsum[r] += __shfl_xor(rsum[r], 4);
                    rsum[r] += __shfl_xor(rsum[r], 8);
                    lrow[qs][r] = lrow[qs][r] * alpha[r] + rsum[r];
                }
                #pragma unroll
                for (int dn = 0; dn < 6; ++dn)
                    #pragma unroll
                    for (int r = 0; r < 4; ++r) O[qs][dn][r] *= alpha[r];
                #pragma unroll
                for (int nt = 0; nt < 4; ++nt)
                    #pragma unroll
                    for (int r = 0; r < 4; ++r)
                        sP[w][lc * 4 + r][nt * 16 + lr] = pv[nt][r];
                #pragma unroll
                for (int ks = 0; ks < 2; ++ks) {
                    const float* pp = &sP[w][lr][ks * 32 + lc * 8];
                    f16x8 ph, pl;
                    #pragma unroll
                    for (int j = 0; j < 8; ++j) {
                        float p = pp[j];
                        half_t h_ = (half_t)p;
                        ph[j] = h_;
                        pl[j] = (half_t)(p - (float)h_);
                    }
                    #pragma unroll
                    for (int dn = 0; dn < 6; ++dn) {
                        f16x8 vh = *(const f16x8*)&sVT[dn * 16 + lr][ks * 32 + lc * 8];
                        f16x8 vl = *(const f16x8*)&sVT[96 + dn * 16 + lr][ks * 32 + lc * 8];
                        O[qs][dn] = __builtin_amdgcn_mfma_f32_16x16x32_f16(ph, vh, O[qs][dn], 0, 0, 0);
                        O[qs][dn] = __builtin_amdgcn_mfma_f32_16x16x32_f16(ph, vl, O[qs][dn], 0, 0, 0);
                        O[qs][dn] = __builtin_amdgcn_mfma_f32_16x16x32_f16(pl, vh, O[qs][dn], 0, 0, 0);
                    }
                }
            }
        }
        #pragma unroll
        for (int qs = 0; qs < 2; ++qs) {
            const int qrow0 = (pass * 2 + qs) * 64 + w * 16;
            #pragma unroll
            for (int r = 0; r < 4; ++r) {
                int qrow = qrow0 + lc * 4 + r;
                if (qrow >= Wn) continue;
                float inv = 1.0f / lrow[qs][r];
                #pragma unroll
                for (int dn = 0; dn < 6; ++dn) {
                    float val = O[qs][dn][r] * inv;
                    half_t hi = (half_t)val;
                    half_t lo = (half_t)(val - (float)hi);
                    size_t o = base + (size_t)qrow * 192 + dn * 16 + lr;
                    qc[o] = hi;
                    qc[o + 96] = lo;
                }
            }
        }
    }
}

// ---------------- row LayerNorm (optional fused fp16-pair split output) -----

template<int SPLIT>
__global__ __launch_bounds__(256) void k_ln(const float* __restrict__ X, const float* __restrict__ g,
                                            const float* __restrict__ bt, float* __restrict__ Y,
                                            half_t* __restrict__ Y16) {
    const int r = blockIdx.x, tid = threadIdx.x;
    __shared__ float red[256];
    const float* x = X + (size_t)r * Dd;
    float x0 = x[tid], x1 = x[tid + 256], x2 = x[tid + 512];
    red[tid] = x0 + x1 + x2; __syncthreads();
    for (int s = 128; s > 0; s >>= 1) { if (tid < s) red[tid] += red[tid + s]; __syncthreads(); }
    float mean = red[0] * (1.0f / 768.0f);
    __syncthreads();
    float d0 = x0 - mean, d1 = x1 - mean, d2 = x2 - mean;
    red[tid] = d0 * d0 + d1 * d1 + d2 * d2; __syncthreads();
    for (int s = 128; s > 0; s >>= 1) { if (tid < s) red[tid] += red[tid + s]; __syncthreads(); }
    float rs = rsqrtf(red[0] * (1.0f / 768.0f) + 1e-5f);
    float* y = Y + (size_t)r * Dd;
    float y0 = d0 * rs * g[tid]       + bt[tid];
    float y1 = d1 * rs * g[tid + 256] + bt[tid + 256];
    float y2 = d2 * rs * g[tid + 512] + bt[tid + 512];
    y[tid] = y0; y[tid + 256] = y1; y[tid + 512] = y2;
    if (SPLIT) {
        half_t* h = Y16 + (size_t)r * 1536;
        float t0 = y0 * 16.f, t1 = y1 * 16.f, t2 = y2 * 16.f;
        half_t h0 = (half_t)t0, h1 = (half_t)t1, h2 = (half_t)t2;
        h[tid] = h0; h[tid + 256] = h1; h[tid + 512] = h2;
        h[768 + tid] = (half_t)(t0 - (float)h0);
        h[768 + tid + 256] = (half_t)(t1 - (float)h1);
        h[768 + tid + 512] = (half_t)(t2 - (float)h2);
    }
}

// ---------------- final LN + 2-class linear + softmax + argmax --------------

__global__ __launch_bounds__(256) void k_final(const float* __restrict__ X, const float* __restrict__ g,
                                               const float* __restrict__ bt, const float* __restrict__ lw,
                                               const float* __restrict__ lb, float* __restrict__ out) {
    const int r = blockIdx.x, tid = threadIdx.x;
    __shared__ float red[256];
    const float* x = X + (size_t)r * Dd;
    float x0 = x[tid], x1 = x[tid + 256], x2 = x[tid + 512];
    red[tid] = x0 + x1 + x2; __syncthreads();
    for (int s = 128; s > 0; s >>= 1) { if (tid < s) red[tid] += red[tid + s]; __syncthreads(); }
    float mean = red[0] * (1.0f / 768.0f);
    __syncthreads();
    float d0 = x0 - mean, d1 = x1 - mean, d2 = x2 - mean;
    red[tid] = d0 * d0 + d1 * d1 + d2 * d2; __syncthreads();
    for (int s = 128; s > 0; s >>= 1) { if (tid < s) red[tid] += red[tid + s]; __syncthreads(); }
    float rs = rsqrtf(red[0] * (1.0f / 768.0f) + 1e-5f);
    __syncthreads();
    float n0 = d0 * rs * g[tid]       + bt[tid];
    float n1 = d1 * rs * g[tid + 256] + bt[tid + 256];
    float n2 = d2 * rs * g[tid + 512] + bt[tid + 512];
    float l0 = n0 * lw[2 * tid]     + n1 * lw[2 * (tid + 256)]     + n2 * lw[2 * (tid + 512)];
    float l1 = n0 * lw[2 * tid + 1] + n1 * lw[2 * (tid + 256) + 1] + n2 * lw[2 * (tid + 512) + 1];
    red[tid] = l0; __syncthreads();
    for (int s = 128; s > 0; s >>= 1) { if (tid < s) red[tid] += red[tid + s]; __syncthreads(); }
    l0 = red[0]; __syncthreads();
    red[tid] = l1; __syncthreads();
    for (int s = 128; s > 0; s >>= 1) { if (tid < s) red[tid] += red[tid + s]; __syncthreads(); }
    l1 = red[0];
    if (tid == 0) {
        l0 += lb[0]; l1 += lb[1];
        float m = fmaxf(l0, l1);
        float e0 = expf(l0 - m), e1 = expf(l1 - m);
        float inv = 1.0f / (e0 + e1);
        out[2 * r] = e0 * inv;
        out[2 * r + 1] = e1 * inv;
        out[2 * NROWS + r] = (l1 > l0) ? 1.0f : 0.0f;
    }
}

// ---------------- launch --------------------------------------------------

extern "C" void kernel_launch(void* const* d_in, const int* in_sizes, int n_in,
                              void* d_out, int out_size, void* d_ws, size_t ws_size,
                              hipStream_t stream) {
    const float* ob  = (const float*)d_in[0];
    const int*   wid = (const int*)d_in[1];
    const float* Wq  = (const float*)d_in[2];  const float* bq  = (const float*)d_in[3];
    const float* Wk  = (const float*)d_in[4];  const float* bk  = (const float*)d_in[5];
    const float* Wv  = (const float*)d_in[6];  const float* bv  = (const float*)d_in[7];
    const float* Wo  = (const float*)d_in[8];  const float* bo  = (const float*)d_in[9];
    const float* g1  = (const float*)d_in[10]; const float* b1  = (const float*)d_in[11];
    const float* W1f = (const float*)d_in[12]; const float* b1f = (const float*)d_in[13];
    const float* W2f = (const float*)d_in[14]; const float* b2f = (const float*)d_in[15];
    const float* g2  = (const float*)d_in[16]; const float* b2  = (const float*)d_in[17];
    const float* ng  = (const float*)d_in[18]; const float* nb  = (const float*)d_in[19];
    const float* lw  = (const float*)d_in[20]; const float* lb  = (const float*)d_in[21];
    float* out = (float*)d_out;

    char* ws = (char*)d_ws;
    const size_t MB = 1u << 20;
    const size_t SLOT = 48 * MB;
    int* fi = (int*)ws;
    float* bcat = (float*)(ws + 262144);
    char* S1 = ws + MB;
    char* S2 = S1 + SLOT;
    char* S3 = S2 + SLOT;
    char* S4 = S3 + SLOT;                      // total 193 MiB (proven OK)

    half_t* feat16 = (half_t*)S1;              // interleaved hi|lo, row = 1536 halves
    half_t* q16    = (half_t*)S2;              // [bh][256][192] -> ctx16 in-place
    half_t* k16    = (half_t*)S3;
    half_t* v16    = (half_t*)S4;
    float*  t1     = (float*)S3;               // Wo out (k16 consumed)
    float*  xbuf   = (float*)S4;               // LN1 out; FFN2 accumulates in-place
    half_t* x16    = (half_t*)S2;              // LN1 split out (ctx consumed by Wo)
    half_t* ffh_h  = (half_t*)S1;              // per-N-chunk hidden hi [row][1024]
    half_t* ffh_l  = (half_t*)S3;              // per-N-chunk hidden lo [row][1024]
    float*  x2     = (float*)S2;               // LN2 out (x16 consumed)

    // weight prep -> concat-K B' panels [N][3K] = [hi|hi|lo]
    k_wsplit<<<dim3(24, 24), dim3(32, 8), 0, stream>>>(Wq, 768, 768, OFF_QKV,                   768, 0);
    k_wsplit<<<dim3(24, 24), dim3(32, 8), 0, stream>>>(Wk, 768, 768, OFF_QKV + 768ul * 2304,    768, 0);
    k_wsplit<<<dim3(24, 24), dim3(32, 8), 0, stream>>>(Wv, 768, 768, OFF_QKV + 1536ul * 2304,   768, 0);
    k_wsplit<<<dim3(24, 24), dim3(32, 8), 0, stream>>>(Wo, 768, 768, OFF_WO,                    768, 0);
    k_wsplit<<<dim3(96, 24), dim3(32, 8), 0, stream>>>(W1f, 768, 3072, OFF_W1,                  768, 0);
    k_wsplit<<<dim3(24, 96), dim3(32, 8), 0, stream>>>(W2f, 3072, 768, OFF_W2,                 1024, 768ul * 3072);
    k_bcat<<<9, 256, 0, stream>>>(bq, bk, bv, bcat);

    k_init_fi<<<(Bsz * Wn + 255) / 256, 256, 0, stream>>>(fi);
    k_scan<<<(Bsz * Tt) / 256, 256, 0, stream>>>(wid, fi);
    k_gather<<<(NROWS * 192 + 255) / 256, 256, 0, stream>>>((const float4*)ob, fi, feat16);

    // fused QKV: M=16320 N=2304 K=768 (K'=2304), grid 9x64=576
    k_gemm256<5, 0><<<dim3(9, 64), 512, 0, stream>>>(
        feat16, feat16 + 768, 1536, OFF_QKV, bcat, nullptr, q16, nullptr, NROWS, 2304, 768);

    k_attn2<<<Bsz * Hh, 256, 0, stream>>>(q16, k16, v16);     // ctx overwrites q16

    // t1 = feat + ctx@Wo + bo ; x = LN1(t1)
    k_gemm256<1, 1><<<dim3(3, 64), 512, 0, stream>>>(
        q16, q16 + 96, 0, OFF_WO, bo, feat16, t1, nullptr, NROWS, 768, 768);
    k_ln<1><<<NROWS, 256, 0, stream>>>(t1, g1, b1, xbuf, x16);

    // FFN in 3 N-chunks of 1024: FFN1 grid 4x64=256 (exact), FFN2 3x64=192,
    // FFN2 accumulates into xbuf in-place (chunk0 adds bias+residual).
    for (int c = 0; c < 3; ++c) {
        k_gemm256<2, 0><<<dim3(4, 64), 512, 0, stream>>>(
            x16, x16 + 768, 1536, OFF_W1 + (size_t)c * 1024 * 2304, b1f + c * 1024,
            nullptr, ffh_h, ffh_l, NROWS, 1024, 768);
        if (c == 0)
            k_gemm256<3, 0><<<dim3(3, 64), 512, 0, stream>>>(
                ffh_h, ffh_l, 1024, OFF_W2, b2f, xbuf, xbuf, nullptr, NROWS, 768, 1024);
        else
            k_gemm256<4, 0><<<dim3(3, 64), 512, 0, stream>>>(
                ffh_h, ffh_l, 1024, OFF_W2 + (size_t)c * 768 * 3072, b2f,
                nullptr, xbuf, nullptr, NROWS, 768, 1024);
    }

    k_ln<0><<<NROWS, 256, 0, stream>>>(xbuf, g2, b2, x2, nullptr);
    k_final<<<NROWS, 256, 0, stream>>>(x2, ng, nb, lw, lb, out);
}

// Round 2
// 1132.105 us; speedup vs baseline: 1.0650x; 1.0650x over previous
//
#include <hip/hip_runtime.h>
#include <cmath>

#define Bsz 64
#define Tt  512
#define Dd  768
#define Wn  255
#define Hh  8
#define DHd 96
#define NROWS (Bsz*Wn)   // 16320

typedef _Float16 half_t;
typedef _Float16 f16x8 __attribute__((ext_vector_type(8)));
typedef _Float16 f16x4 __attribute__((ext_vector_type(4)));
typedef float f32x4 __attribute__((ext_vector_type(4)));

// ---- split-fp16 weights as concatenated-K B' panels: [N][3K] = [Bh | Bh | Bl]
// A' = [Ah | Al | Ah] handled by per-tile source mapping. scales: W x64, act x16,
// epilogue descale 1/1024. ~40.5 MiB static device memory.
#define OFF_QKV 0            // 2304 x 2304
#define OFF_WO  5308416      //  768 x 2304
#define OFF_W1  7077888      // 3072 x 2304
#define OFF_W2  14155776     // 3 chunks x [768 x 3072]  (K split 1024 each)
#define SLOTH 25165824       // halves per 48 MiB workspace slot (q16->k16->v16)
__device__ __align__(16) half_t g_w16[21233664];

__device__ __forceinline__ void gload16(const half_t* g, half_t* l) {
    __builtin_amdgcn_global_load_lds((const __attribute__((address_space(1))) void*)g,
                                     (__attribute__((address_space(3))) void*)l, 16, 0, 0);
}

template<int N> __device__ __forceinline__ void waitv() {
    if constexpr (N == 0) asm volatile("s_waitcnt vmcnt(0)" ::: "memory");
    else if constexpr (N == 2) asm volatile("s_waitcnt vmcnt(2)" ::: "memory");
    else if constexpr (N == 3) asm volatile("s_waitcnt vmcnt(3)" ::: "memory");
    else if constexpr (N == 4) asm volatile("s_waitcnt vmcnt(4)" ::: "memory");
}

// ---------------- gather: first-subtoken index + feature copy ----------------

__global__ void k_init_fi(int* fi) {
    int i = blockIdx.x * 256 + threadIdx.x;
    if (i < Bsz * Wn) fi[i] = 0x7fffffff;
}

__global__ void k_scan(const int* __restrict__ wid, int* __restrict__ fi) {
    int i = blockIdx.x * 256 + threadIdx.x;   // over B*T
    if (i >= Bsz * Tt) return;
    int b = i / Tt, t = i % Tt;
    int w = wid[i];
    if (w >= 0 && w < Wn) atomicMin(&fi[b * Wn + w], t);
}

__global__ void k_bcat(const float* __restrict__ bq, const float* __restrict__ bk,
                       const float* __restrict__ bv, float* __restrict__ o) {
    int i = blockIdx.x * 256 + threadIdx.x;
    if (i < 768) o[i] = bq[i];
    else if (i < 1536) o[i] = bk[i - 768];
    else if (i < 2304) o[i] = bv[i - 1536];
}

// gather directly into interleaved fp16 hi/lo records (row = 1536 halves: hi[768]|lo[768])
__global__ void k_gather(const float4* __restrict__ ob, const int* __restrict__ fi,
                         half_t* __restrict__ f16) {
    int i = blockIdx.x * 256 + threadIdx.x;   // over NROWS*192
    if (i >= NROWS * 192) return;
    int r = i / 192, c = i % 192;
    int b = r / Wn;
    int idx = fi[r];
    if (idx == 0x7fffffff) idx = 0;           // argmax(all-False) == 0
    float4 v = ob[((size_t)b * Tt + idx) * 192 + c];
    float a0 = v.x * 16.f, a1 = v.y * 16.f, a2 = v.z * 16.f, a3 = v.w * 16.f;
    half_t h0 = (half_t)a0, h1 = (half_t)a1, h2 = (half_t)a2, h3 = (half_t)a3;
    f16x4 hv = {h0, h1, h2, h3};
    f16x4 lv = {(half_t)(a0 - (float)h0), (half_t)(a1 - (float)h1),
                (half_t)(a2 - (float)h2), (half_t)(a3 - (float)h3)};
    size_t off = (size_t)r * 1536 + c * 4;
    *(f16x4*)&f16[off] = hv;
    *(f16x4*)&f16[off + 768] = lv;
}

// ---- weight transpose+split: W[K,N] -> B'[n][3*Kseg] = [hi|hi|lo], chunked by Kseg

__global__ void k_wsplit(const float* __restrict__ Wm, int K, int N,
                         size_t obase, int Kseg, size_t cstride) {
    __shared__ float sm[32][33];
    const int tx = threadIdx.x, ty = threadIdx.y;
    const int n0 = blockIdx.x * 32, k0 = blockIdx.y * 32;
    #pragma unroll
    for (int r = 0; r < 4; ++r)
        sm[ty + r * 8][tx] = Wm[(size_t)(k0 + ty + r * 8) * N + n0 + tx];
    __syncthreads();
    #pragma unroll
    for (int r = 0; r < 4; ++r) {
        float v = 64.f * sm[tx][ty + r * 8];
        half_t hi = (half_t)v;
        half_t lo = (half_t)(v - (float)hi);
        int k = k0 + tx;
        int n = n0 + ty + r * 8;
        int c = k / Kseg, kk = k - c * Kseg;
        half_t* o = g_w16 + obase + (size_t)c * cstride + (size_t)n * (3 * Kseg) + kk;
        o[0] = hi; o[Kseg] = hi; o[2 * Kseg] = lo;
    }
}

// ---------------- 256xNTILE split-fp16 MFMA GEMM, counted-vmcnt schedule -----
// 512 thr = 8 waves (2M x 4N), per-wave 128 x (NCH*16) out, BK=64, dbuf LDS.
// NTILE = NCH*64. Grid shaped so blocks/CU is an integer (tile quantization):
//   QKV  N=2304 NCH=3 -> 768 blocks = 3/CU ;  Wo/FFN2 N=768 NCH=3 -> 256 = 1/CU
//   FFN1 N=1024 NCH=4 -> 256 blocks = 1/CU
// LDS per buffer: A 4 chunks (64rx64k) + B NCH chunks; chunk row-major,
// col XOR-swizzled (j ^= row&7) via pre-swizzled global src + swizzled ds_read.
// Per K-tile two sub-phases. Stage issue order: sub0 -> next B0..B(NCH-1),
// sub1 -> next A0,A2,A1,A3. Waits: mid-tile vmcnt(NCH) (drains A1,A3; leaves
// next B), boundary vmcnt(2) (leaves A1,A3). Never 0 in steady state.
// K' = 3K concat: segment 0 -> Ah, 1 -> Al, 2 -> Ah (B' rows prebuilt).
// MODE 5: fused QKV -> q16/k16/v16 head-major [bh][256][hi96|lo96]
// MODE 1: fp32 out + interleaved fp16-pair residual (O-proj); AMODE 1: ctx head-major A
// MODE 2: relu -> fp16 hi/lo plane pair x16 (FFN1 N-chunk)
// MODE 3: fp32 out = acc + bias + res (in-place over res OK: same-thread RMW)
// MODE 4: fp32 out += acc (no bias) -- FFN2 K-chunk accumulation

__device__ __forceinline__ void stage_b(const half_t* B, int Kp3, int col0,
                                        int t, int c, half_t* dst, int tid) {
    int gc = col0 + c * 64 + (tid >> 3);
    int sj = (tid & 7) ^ ((tid >> 3) & 7);
    gload16(B + (size_t)gc * Kp3 + (size_t)t * 64 + sj * 8,
            dst + 16384 + c * 4096 + (tid >> 6) * 512);
}

__device__ __forceinline__ void stage_a0(const half_t* Ap, int lda, int row0, int M,
                                         int kk, int c, half_t* dst, int tid) {
    int gr = row0 + c * 64 + (tid >> 3); if (gr > M - 1) gr = M - 1;
    int sj = (tid & 7) ^ ((tid >> 3) & 7);
    gload16(Ap + (size_t)gr * lda + kk + sj * 8, dst + c * 4096 + (tid >> 6) * 512);
}

__device__ __forceinline__ void stage_a1(const half_t* qcb, int row0, int M,
                                         int kk, int soff, int c, half_t* dst, int tid) {
    int gr = row0 + c * 64 + (tid >> 3); if (gr > M - 1) gr = M - 1;
    int sj = (tid & 7) ^ ((tid >> 3) & 7);
    int k = kk + sj * 8;
    int h = k / 96, d = k - h * 96;
    int b = gr / 255, wl = gr - b * 255;
    gload16(qcb + ((size_t)(b * 8 + h) * 256 + wl) * 192 + d + soff,
            dst + c * 4096 + (tid >> 6) * 512);
}

template<int MODE, int AMODE, int NCH>
__global__ __launch_bounds__(512, 2) void k_gemm256(
    const half_t* __restrict__ Ah, const half_t* __restrict__ Al, int lda,
    size_t boff, const float* __restrict__ bias,
    const void* res, void* out0, void* out1,
    int M, int N, int K) {
    __shared__ half_t sm[2][16384 + NCH * 4096];
    const int tid = threadIdx.x;
    const int w = tid >> 6, l = tid & 63;
    const int wm = w >> 2, wn = w & 3;
    const int fr = l & 15, q4 = l >> 4;
    const int ck0 = (q4 * 8) ^ ((fr & 7) << 3);   // swizzled col (halves), ks=0
    const int ck1 = ck0 ^ 32;                     // ks=1
    const half_t* Bsrc = g_w16 + boff;
    const int Kp3 = 3 * K, NT = Kp3 >> 6;

    // XCD-locality swizzle (nwg % 8 == 0 for all our grids)
    int lin = blockIdx.y * gridDim.x + blockIdx.x;
    int nwg = gridDim.x * gridDim.y;
    int wg = (lin & 7) * (nwg >> 3) + (lin >> 3);
    int by = wg / gridDim.x, bx = wg - by * gridDim.x;
    const int row0 = by * 256, col0 = bx * (NCH * 64);

    f32x4 acc[8][NCH];
    #pragma unroll
    for (int m = 0; m < 8; ++m)
        #pragma unroll
        for (int n = 0; n < NCH; ++n) acc[m][n] = (f32x4){0.f, 0.f, 0.f, 0.f};

    // prologue: stage tile 0 in steady-state issue order [B*, A0,A2,A1,A3]
    {
        half_t* d0 = &sm[0][0];
        #pragma unroll
        for (int c = 0; c < NCH; ++c) stage_b(Bsrc, Kp3, col0, 0, c, d0, tid);
        if (AMODE == 0) {
            stage_a0(Ah, lda, row0, M, 0, 0, d0, tid);
            stage_a0(Ah, lda, row0, M, 0, 2, d0, tid);
            stage_a0(Ah, lda, row0, M, 0, 1, d0, tid);
            stage_a0(Ah, lda, row0, M, 0, 3, d0, tid);
        } else {
            stage_a1(Ah, row0, M, 0, 0, 0, d0, tid);
            stage_a1(Ah, row0, M, 0, 0, 2, d0, tid);
            stage_a1(Ah, row0, M, 0, 0, 1, d0, tid);
            stage_a1(Ah, row0, M, 0, 0, 3, d0, tid);
        }
    }
    waitv<2>();
    __builtin_amdgcn_s_barrier();
    asm volatile("" ::: "memory");

    for (int t = 0; t < NT; ++t) {
        const int p = t & 1;
        half_t* nxtb = &sm[p ^ 1][0];
        const half_t* pA = &sm[p][0] + wm * 8192;
        const half_t* pB = &sm[p][16384];
        const bool pf = (t + 1) < NT;
        const int kn = (t + 1) << 6;
        const int seg = (kn >= 2 * K) ? 2 : ((kn >= K) ? 1 : 0);
        const int kkn = kn - seg * K;
        const half_t* An = (seg == 1) ? Al : Ah;
        const int soff = (seg == 1) ? 96 : 0;

        // ---- sub0: B frags (held for whole tile) + A m0..3, stage next B ----
        f16x8 b0[NCH], b1[NCH], a0[4], a1[4];
        #pragma unroll
        for (int n = 0; n < NCH; ++n) {
            const int cb = wn * (NCH * 16) + n * 16;
            const half_t* p_ = &pB[(cb >> 6) * 4096 + ((cb & 63) + fr) * 64];
            b0[n] = *(const f16x8*)&p_[ck0];
            b1[n] = *(const f16x8*)&p_[ck1];
        }
        #pragma unroll
        for (int m = 0; m < 4; ++m) {
            a0[m] = *(const f16x8*)&pA[m * 1024 + fr * 64 + ck0];
            a1[m] = *(const f16x8*)&pA[m * 1024 + fr * 64 + ck1];
        }
        if (pf) {
            #pragma unroll
            for (int c = 0; c < NCH; ++c) stage_b(Bsrc, Kp3, col0, t + 1, c, nxtb, tid);
        }
        __builtin_amdgcn_s_setprio(1);
        #pragma unroll
        for (int m = 0; m < 4; ++m)
            #pragma unroll
            for (int n = 0; n < NCH; ++n) {
                acc[m][n] = __builtin_amdgcn_mfma_f32_16x16x32_f16(a0[m], b0[n], acc[m][n], 0, 0, 0);
                acc[m][n] = __builtin_amdgcn_mfma_f32_16x16x32_f16(a1[m], b1[n], acc[m][n], 0, 0, 0);
            }
        __builtin_amdgcn_s_setprio(0);
        if (pf) waitv<NCH>();
        else    waitv<0>();
        __builtin_amdgcn_s_barrier();
        asm volatile("" ::: "memory");

        // ---- sub1: A m4..7, stage next A (order 0,2,1,3) ----
        #pragma unroll
        for (int m = 0; m < 4; ++m) {
            a0[m] = *(const f16x8*)&pA[4096 + m * 1024 + fr * 64 + ck0];
            a1[m] = *(const f16x8*)&pA[4096 + m * 1024 + fr * 64 + ck1];
        }
        if (pf) {
            if (AMODE == 0) {
                stage_a0(An, lda, row0, M, kkn, 0, nxtb, tid);
                stage_a0(An, lda, row0, M, kkn, 2, nxtb, tid);
                stage_a0(An, lda, row0, M, kkn, 1, nxtb, tid);
                stage_a0(An, lda, row0, M, kkn, 3, nxtb, tid);
            } else {
                stage_a1(Ah, row0, M, kkn, soff, 0, nxtb, tid);
                stage_a1(Ah, row0, M, kkn, soff, 2, nxtb, tid);
                stage_a1(Ah, row0, M, kkn, soff, 1, nxtb, tid);
                stage_a1(Ah, row0, M, kkn, soff, 3, nxtb, tid);
            }
        }
        __builtin_amdgcn_s_setprio(1);
        #pragma unroll
        for (int m = 0; m < 4; ++m)
            #pragma unroll
            for (int n = 0; n < NCH; ++n) {
                acc[4 + m][n] = __builtin_amdgcn_mfma_f32_16x16x32_f16(a0[m], b0[n], acc[4 + m][n], 0, 0, 0);
                acc[4 + m][n] = __builtin_amdgcn_mfma_f32_16x16x32_f16(a1[m], b1[n], acc[4 + m][n], 0, 0, 0);
            }
        __builtin_amdgcn_s_setprio(0);
        if (pf) {
            waitv<2>();
            __builtin_amdgcn_s_barrier();
            asm volatile("" ::: "memory");
        }
    }

    // ---- epilogue ----
    const float dsc = 1.0f / 1024.0f;
    #pragma unroll
    for (int m = 0; m < 8; ++m) {
        #pragma unroll
        for (int r = 0; r < 4; ++r) {
            const int row = row0 + wm * 128 + m * 16 + q4 * 4 + r;
            if (row >= M) continue;
            #pragma unroll
            for (int n = 0; n < NCH; ++n) {
                const int col = col0 + wn * (NCH * 16) + n * 16 + fr;
                float vv = acc[m][n][r] * dsc;
                if (MODE != 4) vv += bias[col];
                if (MODE == 5) {
                    int part = col / 768, cc = col - part * 768;
                    int h = cc / 96, d = cc - h * 96;
                    int b = row / 255, wl = row - b * 255;
                    float t16 = vv * 16.f;
                    half_t hi = (half_t)t16;
                    half_t lo = (half_t)(t16 - (float)hi);
                    half_t* dstp = (half_t*)out0 + (size_t)part * SLOTH;
                    size_t o = ((size_t)(b * 8 + h) * 256 + wl) * 192 + d;
                    dstp[o] = hi; dstp[o + 96] = lo;
                } else if (MODE == 1) {
                    const half_t* rp = (const half_t*)res;
                    vv += ((float)rp[(size_t)row * 1536 + col] +
                           (float)rp[(size_t)row * 1536 + 768 + col]) * 0.0625f;
                    ((float*)out0)[(size_t)row * N + col] = vv;
                } else if (MODE == 2) {
                    vv = fmaxf(vv, 0.f);
                    float t16 = vv * 16.f;
                    half_t hi = (half_t)t16;
                    ((half_t*)out0)[(size_t)row * N + col] = hi;
                    ((half_t*)out1)[(size_t)row * N + col] = (half_t)(t16 - (float)hi);
                } else if (MODE == 3) {
                    vv += ((const float*)res)[(size_t)row * N + col];
                    ((float*)out0)[(size_t)row * N + col] = vv;
                } else {   // MODE 4: accumulate (same-thread RMW, stream-serialized)
                    float* op = (float*)out0 + (size_t)row * N + col;
                    *op += vv;
                }
            }
        }
    }
}

// ---------------- flash MFMA attention, split-fp16, one block per (b,h) ------
// (unchanged from previous verified version)

__global__ __launch_bounds__(256, 2) void k_attn2(half_t* __restrict__ qc,
                                                  const half_t* __restrict__ kk16,
                                                  const half_t* __restrict__ vv16) {
    __shared__ half_t sK[64][200];
    __shared__ half_t sVT[192][72];
    __shared__ float  sP[4][16][68];
    const int tid = threadIdx.x;
    const int w = tid >> 6, l = tid & 63;
    const int lr = l & 15, lc = l >> 4;
    const size_t base = (size_t)blockIdx.x * 49152;
    const float ssc = 0.10206207261596575f / 256.0f;

    for (int pass = 0; pass < 2; ++pass) {
        f32x4 O[2][6];
        float mrow[2][4], lrow[2][4];
        #pragma unroll
        for (int qs = 0; qs < 2; ++qs) {
            #pragma unroll
            for (int dn = 0; dn < 6; ++dn) O[qs][dn] = (f32x4){0.f, 0.f, 0.f, 0.f};
            #pragma unroll
            for (int r = 0; r < 4; ++r) { mrow[qs][r] = -3e38f; lrow[qs][r] = 0.f; }
        }
        for (int kt = 0; kt < 4; ++kt) {
            __syncthreads();
            #pragma unroll
            for (int c = 0; c < 6; ++c) {
                int ch = w + c * 4;
                *(f16x8*)&sK[l][ch * 8] =
                    *(const f16x8*)(kk16 + base + (size_t)(kt * 64 + l) * 192 + ch * 8);
            }
            #pragma unroll
            for (int c = 0; c < 6; ++c) {
                int ch = w + c * 4;
                f16x8 vv = *(const f16x8*)(vv16 + base + (size_t)(kt * 64 + l) * 192 + ch * 8);
                #pragma unroll
                for (int j = 0; j < 8; ++j) sVT[ch * 8 + j][l] = vv[j];
            }
            __syncthreads();
            #pragma unroll
            for (int qs = 0; qs < 2; ++qs) {
                const int qrow0 = (pass * 2 + qs) * 64 + w * 16;
                f16x8 qf0[3], qf1[3];
                #pragma unroll
                for (int s = 0; s < 3; ++s) {
                    qf0[s] = *(const f16x8*)(qc + base + (size_t)(qrow0 + lr) * 192 + s * 32 + lc * 8);
                    qf1[s] = *(const f16x8*)(qc + base + (size_t)(qrow0 + lr) * 192 + 96 + s * 32 + lc * 8);
                }
                f32x4 sacc[4];
                #pragma unroll
                for (int nt = 0; nt < 4; ++nt) sacc[nt] = (f32x4){0.f, 0.f, 0.f, 0.f};
                #pragma unroll
                for (int s = 0; s < 3; ++s)
                    #pragma unroll
                    for (int nt = 0; nt < 4; ++nt) {
                        f16x8 kh = *(const f16x8*)&sK[nt * 16 + lr][s * 32 + lc * 8];
                        f16x8 klo = *(const f16x8*)&sK[nt * 16 + lr][96 + s * 32 + lc * 8];
                        sacc[nt] = __builtin_amdgcn_mfma_f32_16x16x32_f16(qf0[s], kh, sacc[nt], 0, 0, 0);
                        sacc[nt] = __builtin_amdgcn_mfma_f32_16x16x32_f16(qf0[s], klo, sacc[nt], 0, 0, 0);
                        sacc[nt] = __builtin_amdgcn_mfma_f32_16x16x32_f16(qf1[s], kh, sacc[nt], 0, 0, 0);
                    }
                float sv[4][4], mx[4] = {-3e38f, -3e38f, -3e38f, -3e38f};
                #pragma unroll
                for (int nt = 0; nt < 4; ++nt) {
                    int key = kt * 64 + nt * 16 + lr;
                    #pragma unroll
                    for (int r = 0; r < 4; ++r) {
                        float s_ = sacc[nt][r] * ssc;
                        if (key >= 255) s_ = -3e38f;
                        sv[nt][r] = s_;
                        mx[r] = fmaxf(mx[r], s_);
                    }
                }
                #pragma unroll
                for (int r = 0; r < 4; ++r) {
                    mx[r] = fmaxf(mx[r], __shfl_xor(mx[r], 1));
                    mx[r] = fmaxf(mx[r], __shfl_xor(mx[r], 2));
                    mx[r] = fmaxf(mx[r], __shfl_xor(mx[r], 4));
                    mx[r] = fmaxf(mx[r], __shfl_xor(mx[r], 8));
                }
                float alpha[4], rsum[4];
                #pragma unroll
                for (int r = 0; r < 4; ++r) {
                    float mn = fmaxf(mrow[qs][r], mx[r]);
                    alpha[r] = __expf(mrow[qs][r] - mn);
                    mrow[qs][r] = mn;
                    rsum[r] = 0.f;
                }
                float pv[4][4];
                #pragma unroll
                for (int nt = 0; nt < 4; ++nt)
                    #pragma unroll
                    for (int r = 0; r < 4; ++r) {
                        float p = __expf(sv[nt][r] - mrow[qs][r]);
                        pv[nt][r] = p;
                        rsum[r] += p;
                    }
                #pragma unroll
                for (int r = 0; r < 4; ++r) {
                    rsum[r] += __shfl_xor(rsum[r], 1);
                    rsum[r] += __shfl_xor(rsum[r], 2);
                    rsum[r] += __shfl_xor(rsum[r], 4);
                    rsum[r] += __shfl_xor(rsum[r], 8);
                    lrow[qs][r] = lrow[qs][r] * alpha[r] + rsum[r];
                }
                #pragma unroll
                for (int dn = 0; dn < 6; ++dn)
                    #pragma unroll
                    for (int r = 0; r < 4; ++r) O[qs][dn][r] *= alpha[r];
                #pragma unroll
                for (int nt = 0; nt < 4; ++nt)
                    #pragma unroll
                    for (int r = 0; r < 4; ++r)
                        sP[w][lc * 4 + r][nt * 16 + lr] = pv[nt][r];
                #pragma unroll
                for (int ks = 0; ks < 2; ++ks) {
                    const float* pp = &sP[w][lr][ks * 32 + lc * 8];
                    f16x8 ph, pl;
                    #pragma unroll
                    for (int j = 0; j < 8; ++j) {
                        float p = pp[j];
                        half_t h_ = (half_t)p;
                        ph[j] = h_;
                        pl[j] = (half_t)(p - (float)h_);
                    }
                    #pragma unroll
                    for (int dn = 0; dn < 6; ++dn) {
                        f16x8 vh = *(const f16x8*)&sVT[dn * 16 + lr][ks * 32 + lc * 8];
                        f16x8 vl = *(const f16x8*)&sVT[96 + dn * 16 + lr][ks * 32 + lc * 8];
                        O[qs][dn] = __builtin_amdgcn_mfma_f32_16x16x32_f16(ph, vh, O[qs][dn], 0, 0, 0);
                        O[qs][dn] = __builtin_amdgcn_mfma_f32_16x16x32_f16(ph, vl, O[qs][dn], 0, 0, 0);
                        O[qs][dn] = __builtin_amdgcn_mfma_f32_16x16x32_f16(pl, vh, O[qs][dn], 0, 0, 0);
                    }
                }
            }
        }
        #pragma unroll
        for (int qs = 0; qs < 2; ++qs) {
            const int qrow0 = (pass * 2 + qs) * 64 + w * 16;
            #pragma unroll
            for (int r = 0; r < 4; ++r) {
                int qrow = qrow0 + lc * 4 + r;
                if (qrow >= Wn) continue;
                float inv = 1.0f / lrow[qs][r];
                #pragma unroll
                for (int dn = 0; dn < 6; ++dn) {
                    float val = O[qs][dn][r] * inv;
                    half_t hi = (half_t)val;
                    half_t lo = (half_t)(val - (float)hi);
                    size_t o = base + (size_t)qrow * 192 + dn * 16 + lr;
                    qc[o] = hi;
                    qc[o + 96] = lo;
                }
            }
        }
    }
}

// ---------------- row LayerNorm (optional fused fp16-pair split output) -----

template<int SPLIT>
__global__ __launch_bounds__(256) void k_ln(const float* __restrict__ X, const float* __restrict__ g,
                                            const float* __restrict__ bt, float* __restrict__ Y,
                                            half_t* __restrict__ Y16) {
    const int r = blockIdx.x, tid = threadIdx.x;
    __shared__ float red[256];
    const float* x = X + (size_t)r * Dd;
    float x0 = x[tid], x1 = x[tid + 256], x2 = x[tid + 512];
    red[tid] = x0 + x1 + x2; __syncthreads();
    for (int s = 128; s > 0; s >>= 1) { if (tid < s) red[tid] += red[tid + s]; __syncthreads(); }
    float mean = red[0] * (1.0f / 768.0f);
    __syncthreads();
    float d0 = x0 - mean, d1 = x1 - mean, d2 = x2 - mean;
    red[tid] = d0 * d0 + d1 * d1 + d2 * d2; __syncthreads();
    for (int s = 128; s > 0; s >>= 1) { if (tid < s) red[tid] += red[tid + s]; __syncthreads(); }
    float rs = rsqrtf(red[0] * (1.0f / 768.0f) + 1e-5f);
    float* y = Y + (size_t)r * Dd;
    float y0 = d0 * rs * g[tid]       + bt[tid];
    float y1 = d1 * rs * g[tid + 256] + bt[tid + 256];
    float y2 = d2 * rs * g[tid + 512] + bt[tid + 512];
    y[tid] = y0; y[tid + 256] = y1; y[tid + 512] = y2;
    if (SPLIT) {
        half_t* h = Y16 + (size_t)r * 1536;
        float t0 = y0 * 16.f, t1 = y1 * 16.f, t2 = y2 * 16.f;
        half_t h0 = (half_t)t0, h1 = (half_t)t1, h2 = (half_t)t2;
        h[tid] = h0; h[tid + 256] = h1; h[tid + 512] = h2;
        h[768 + tid] = (half_t)(t0 - (float)h0);
        h[768 + tid + 256] = (half_t)(t1 - (float)h1);
        h[768 + tid + 512] = (half_t)(t2 - (float)h2);
    }
}

// ---------------- final LN + 2-class linear + softmax + argmax --------------

__global__ __launch_bounds__(256) void k_final(const float* __restrict__ X, const float* __restrict__ g,
                                               const float* __restrict__ bt, const float* __restrict__ lw,
                                               const float* __restrict__ lb, float* __restrict__ out) {
    const int r = blockIdx.x, tid = threadIdx.x;
    __shared__ float red[256];
    const float* x = X + (size_t)r * Dd;
    float x0 = x[tid], x1 = x[tid + 256], x2 = x[tid + 512];
    red[tid] = x0 + x1 + x2; __syncthreads();
    for (int s = 128; s > 0; s >>= 1) { if (tid < s) red[tid] += red[tid + s]; __syncthreads(); }
    float mean = red[0] * (1.0f / 768.0f);
    __syncthreads();
    float d0 = x0 - mean, d1 = x1 - mean, d2 = x2 - mean;
    red[tid] = d0 * d0 + d1 * d1 + d2 * d2; __syncthreads();
    for (int s = 128; s > 0; s >>= 1) { if (tid < s) red[tid] += red[tid + s]; __syncthreads(); }
    float rs = rsqrtf(red[0] * (1.0f / 768.0f) + 1e-5f);
    __syncthreads();
    float n0 = d0 * rs * g[tid]       + bt[tid];
    float n1 = d1 * rs * g[tid + 256] + bt[tid + 256];
    float n2 = d2 * rs * g[tid + 512] + bt[tid + 512];
    float l0 = n0 * lw[2 * tid]     + n1 * lw[2 * (tid + 256)]     + n2 * lw[2 * (tid + 512)];
    float l1 = n0 * lw[2 * tid + 1] + n1 * lw[2 * (tid + 256) + 1] + n2 * lw[2 * (tid + 512) + 1];
    red[tid] = l0; __syncthreads();
    for (int s = 128; s > 0; s >>= 1) { if (tid < s) red[tid] += red[tid + s]; __syncthreads(); }
    l0 = red[0]; __syncthreads();
    red[tid] = l1; __syncthreads();
    for (int s = 128; s > 0; s >>= 1) { if (tid < s) red[tid] += red[tid + s]; __syncthreads(); }
    l1 = red[0];
    if (tid == 0) {
        l0 += lb[0]; l1 += lb[1];
        float m = fmaxf(l0, l1);
        float e0 = expf(l0 - m), e1 = expf(l1 - m);
        float inv = 1.0f / (e0 + e1);
        out[2 * r] = e0 * inv;
        out[2 * r + 1] = e1 * inv;
        out[2 * NROWS + r] = (l1 > l0) ? 1.0f : 0.0f;
    }
}

// ---------------- launch --------------------------------------------------

extern "C" void kernel_launch(void* const* d_in, const int* in_sizes, int n_in,
                              void* d_out, int out_size, void* d_ws, size_t ws_size,
                              hipStream_t stream) {
    const float* ob  = (const float*)d_in[0];
    const int*   wid = (const int*)d_in[1];
    const float* Wq  = (const float*)d_in[2];  const float* bq  = (const float*)d_in[3];
    const float* Wk  = (const float*)d_in[4];  const float* bk  = (const float*)d_in[5];
    const float* Wv  = (const float*)d_in[6];  const float* bv  = (const float*)d_in[7];
    const float* Wo  = (const float*)d_in[8];  const float* bo  = (const float*)d_in[9];
    const float* g1  = (const float*)d_in[10]; const float* b1  = (const float*)d_in[11];
    const float* W1f = (const float*)d_in[12]; const float* b1f = (const float*)d_in[13];
    const float* W2f = (const float*)d_in[14]; const float* b2f = (const float*)d_in[15];
    const float* g2  = (const float*)d_in[16]; const float* b2  = (const float*)d_in[17];
    const float* ng  = (const float*)d_in[18]; const float* nb  = (const float*)d_in[19];
    const float* lw  = (const float*)d_in[20]; const float* lb  = (const float*)d_in[21];
    float* out = (float*)d_out;

    char* ws = (char*)d_ws;
    const size_t MB = 1u << 20;
    const size_t SLOT = 48 * MB;
    int* fi = (int*)ws;
    float* bcat = (float*)(ws + 262144);
    char* S1 = ws + MB;
    char* S2 = S1 + SLOT;
    char* S3 = S2 + SLOT;
    char* S4 = S3 + SLOT;                      // total 193 MiB (proven OK)

    half_t* feat16 = (half_t*)S1;              // interleaved hi|lo, row = 1536 halves
    half_t* q16    = (half_t*)S2;              // [bh][256][192] -> ctx16 in-place
    half_t* k16    = (half_t*)S3;
    half_t* v16    = (half_t*)S4;
    float*  t1     = (float*)S3;               // Wo out (k16 consumed)
    float*  xbuf   = (float*)S4;               // LN1 out; FFN2 accumulates in-place
    half_t* x16    = (half_t*)S2;              // LN1 split out (ctx consumed by Wo)
    half_t* ffh_h  = (half_t*)S1;              // per-N-chunk hidden hi [row][1024]
    half_t* ffh_l  = (half_t*)S3;              // per-N-chunk hidden lo [row][1024]
    float*  x2     = (float*)S2;               // LN2 out (x16 consumed)

    // weight prep -> concat-K B' panels [N][3K] = [hi|hi|lo]
    k_wsplit<<<dim3(24, 24), dim3(32, 8), 0, stream>>>(Wq, 768, 768, OFF_QKV,                   768, 0);
    k_wsplit<<<dim3(24, 24), dim3(32, 8), 0, stream>>>(Wk, 768, 768, OFF_QKV + 768ul * 2304,    768, 0);
    k_wsplit<<<dim3(24, 24), dim3(32, 8), 0, stream>>>(Wv, 768, 768, OFF_QKV + 1536ul * 2304,   768, 0);
    k_wsplit<<<dim3(24, 24), dim3(32, 8), 0, stream>>>(Wo, 768, 768, OFF_WO,                    768, 0);
    k_wsplit<<<dim3(96, 24), dim3(32, 8), 0, stream>>>(W1f, 768, 3072, OFF_W1,                  768, 0);
    k_wsplit<<<dim3(24, 96), dim3(32, 8), 0, stream>>>(W2f, 3072, 768, OFF_W2,                 1024, 768ul * 3072);
    k_bcat<<<9, 256, 0, stream>>>(bq, bk, bv, bcat);

    k_init_fi<<<(Bsz * Wn + 255) / 256, 256, 0, stream>>>(fi);
    k_scan<<<(Bsz * Tt) / 256, 256, 0, stream>>>(wid, fi);
    k_gather<<<(NROWS * 192 + 255) / 256, 256, 0, stream>>>((const float4*)ob, fi, feat16);

    // fused QKV: M=16320 N=2304 K=768 (K'=2304), NTILE=192 -> 12x64 = 768 blocks = 3/CU
    k_gemm256<5, 0, 3><<<dim3(12, 64), 512, 0, stream>>>(
        feat16, feat16 + 768, 1536, OFF_QKV, bcat, nullptr, q16, nullptr, NROWS, 2304, 768);

    k_attn2<<<Bsz * Hh, 256, 0, stream>>>(q16, k16, v16);     // ctx overwrites q16

    // t1 = feat + ctx@Wo + bo ; NTILE=192 -> 4x64 = 256 blocks = 1/CU ; x = LN1(t1)
    k_gemm256<1, 1, 3><<<dim3(4, 64), 512, 0, stream>>>(
        q16, q16 + 96, 0, OFF_WO, bo, feat16, t1, nullptr, NROWS, 768, 768);
    k_ln<1><<<NROWS, 256, 0, stream>>>(t1, g1, b1, xbuf, x16);

    // FFN in 3 N-chunks of 1024: FFN1 NTILE=256 -> 256 blocks = 1/CU exact,
    // FFN2 NTILE=192 -> 256 blocks = 1/CU exact; accumulates into xbuf in-place.
    for (int c = 0; c < 3; ++c) {
        k_gemm256<2, 0, 4><<<dim3(4, 64), 512, 0, stream>>>(
            x16, x16 + 768, 1536, OFF_W1 + (size_t)c * 1024 * 2304, b1f + c * 1024,
            nullptr, ffh_h, ffh_l, NROWS, 1024, 768);
        if (c == 0)
            k_gemm256<3, 0, 3><<<dim3(4, 64), 512, 0, stream>>>(
                ffh_h, ffh_l, 1024, OFF_W2, b2f, xbuf, xbuf, nullptr, NROWS, 768, 1024);
        else
            k_gemm256<4, 0, 3><<<dim3(4, 64), 512, 0, stream>>>(
                ffh_h, ffh_l, 1024, OFF_W2 + (size_t)c * 768 * 3072, b2f,
                nullptr, xbuf, nullptr, NROWS, 768, 1024);
    }

    k_ln<0><<<NROWS, 256, 0, stream>>>(xbuf, g2, b2, x2, nullptr);
    k_final<<<NROWS, 256, 0, stream>>>(x2, ng, nb, lw, lb, out);
}